// Round 3
// baseline (294.194 us; speedup 1.0000x reference)
//
#include <hip/hip_runtime.h>
#include <math.h>

#define BB 8
#define PP 2048
#define VV 2562
#define NV 8192
#define FF 16384
#define EPSF 1e-12f
#define HNV 4096   // NV/2  (per-wave half of gt refs)
#define HVV 1281   // VV/2  (per-wave half of pred refs)

// ---------------------------------------------------------------------------
// Kernel 1: per-face normals accumulated in LDS (one block per batch).
// 96 KB LDS accumulator; LDS atomics (random banks, low contention) instead
// of 1.18M global atomics (which cost 36 MB of HBM write-through, 61 us).
// Exclusive batch ownership -> plain coalesced global write, no memset.
// ---------------------------------------------------------------------------
__global__ __launch_bounds__(1024) void face_normals_kernel(
    const float* __restrict__ gtv,   // (B, NV, 3)
    const int*   __restrict__ faces, // (B, FF, 3) int32
    float*       __restrict__ nrm)   // (B, NV, 3)
{
    __shared__ float acc[NV * 3];    // 98304 B
    const int b = blockIdx.x;

    for (int i = threadIdx.x; i < NV * 3; i += 1024) acc[i] = 0.f;
    __syncthreads();

    const int*   fb = faces + (size_t)b * FF * 3;
    const float* vb = gtv   + (size_t)b * NV * 3;

    for (int f = threadIdx.x; f < FF; f += 1024) {
        int i0 = fb[f*3+0], i1 = fb[f*3+1], i2 = fb[f*3+2];

        float v0x = vb[i0*3+0], v0y = vb[i0*3+1], v0z = vb[i0*3+2];
        float v1x = vb[i1*3+0], v1y = vb[i1*3+1], v1z = vb[i1*3+2];
        float v2x = vb[i2*3+0], v2y = vb[i2*3+1], v2z = vb[i2*3+2];

        float e1x = v1x - v0x, e1y = v1y - v0y, e1z = v1z - v0z;
        float e2x = v2x - v0x, e2y = v2y - v0y, e2z = v2z - v0z;

        float fnx = e1y * e2z - e1z * e2y;
        float fny = e1z * e2x - e1x * e2z;
        float fnz = e1x * e2y - e1y * e2x;

        atomicAdd(&acc[i0*3+0], fnx); atomicAdd(&acc[i0*3+1], fny); atomicAdd(&acc[i0*3+2], fnz);
        atomicAdd(&acc[i1*3+0], fnx); atomicAdd(&acc[i1*3+1], fny); atomicAdd(&acc[i1*3+2], fnz);
        atomicAdd(&acc[i2*3+0], fnx); atomicAdd(&acc[i2*3+1], fny); atomicAdd(&acc[i2*3+2], fnz);
    }
    __syncthreads();

    float* nb = nrm + (size_t)b * NV * 3;
    for (int i = threadIdx.x; i < NV * 3; i += 1024) nb[i] = acc[i];
}

// ---------------------------------------------------------------------------
// Kernel 2: NN + loss. Block = 4 waves = 8 points. Wave w: point-group
// g = w>>1 (4 points), ref-half h = w&1. Each wave scans its half of the
// reference set for its 4 points (lane l handles refs l, l+64, ...), using
// the reference's own expanded score  rr - 2 q.r  (|q|^2 is argmin-invariant):
// 3 FMA + cmp + 2 cndmask per pair, rr amortized over 4 points.
// Butterfly shfl argmin (lowest-index tie-break), halves combined via LDS
// (index compare preserves first-occurrence semantics). Lanes 0..7 of wave 0
// do the gathers + loss terms; one atomicAdd(out) per block.
// 2048 blocks * 4 waves = 8192 waves = 8/SIMD (100% occupancy target).
// ---------------------------------------------------------------------------
__global__ __launch_bounds__(256) void nn_loss_kernel(
    const float* __restrict__ pp,   // (B, P, 3)  pred_points
    const float* __restrict__ pv,   // (B, V, 3)  pred_vertices
    const float* __restrict__ gtv,  // (B, NV, 3) gt_vertices
    const float* __restrict__ nrm,  // (B, NV, 3) gt vertex normals
    float*       __restrict__ out)  // scalar accumulator (pre-zeroed)
{
    __shared__ float sdg[2][2][4];  __shared__ int sig[2][2][4];
    __shared__ float sdp[2][2][4];  __shared__ int sip[2][2][4];

    const int lane = threadIdx.x & 63;
    const int wave = threadIdx.x >> 6;
    const int g    = wave >> 1;              // point group 0/1
    const int h    = wave & 1;               // ref half 0/1
    const int b    = blockIdx.x >> 8;        // 256 blocks per batch
    const int pbase = (blockIdx.x & 255) * 8 + g * 4;  // point-in-batch base

    // Negated-doubled query coords (wave-uniform loads, L1 broadcast).
    float m2x[4], m2y[4], m2z[4];
    {
        const float* ppb = pp + ((size_t)b * PP + pbase) * 3;
#pragma unroll
        for (int j = 0; j < 4; ++j) {
            m2x[j] = -2.f * ppb[j*3+0];
            m2y[j] = -2.f * ppb[j*3+1];
            m2z[j] = -2.f * ppb[j*3+2];
        }
    }

    float bd[4]; int bi[4];

    // ---- gt half-scan: 4096 refs = 64 iters, no tail ----
#pragma unroll
    for (int j = 0; j < 4; ++j) { bd[j] = INFINITY; bi[j] = 0; }
    {
        const float* gvb = gtv + ((size_t)b * NV + (size_t)h * HNV) * 3;
        for (int i = 0; i < HNV / 64; ++i) {
            int r = lane + i * 64;
            float rx = gvb[r*3+0], ry = gvb[r*3+1], rz = gvb[r*3+2];
            float rr = fmaf(rx, rx, fmaf(ry, ry, rz * rz));
#pragma unroll
            for (int j = 0; j < 4; ++j) {
                float s = fmaf(m2x[j], rx, fmaf(m2y[j], ry, fmaf(m2z[j], rz, rr)));
                bool take = s < bd[j];       // strict <: lowest idx per lane
                bd[j] = take ? s : bd[j];
                bi[j] = take ? r : bi[j];
            }
        }
    }
#pragma unroll
    for (int j = 0; j < 4; ++j) {
        float d = bd[j]; int idx = bi[j];
#pragma unroll
        for (int off = 32; off; off >>= 1) {
            float od = __shfl_xor(d, off);
            int   oi = __shfl_xor(idx, off);
            if (od < d || (od == d && oi < idx)) { d = od; idx = oi; }
        }
        if (lane == 0) { sdg[g][h][j] = d; sig[g][h][j] = idx + h * HNV; }
    }

    // ---- pred half-scan: 1281 refs = 21 iters, guarded tail ----
#pragma unroll
    for (int j = 0; j < 4; ++j) { bd[j] = INFINITY; bi[j] = 0; }
    {
        const float* pvh = pv + ((size_t)b * VV + (size_t)h * HVV) * 3;
        for (int i = 0; i < (HVV + 63) / 64; ++i) {
            int r = lane + i * 64;
            bool ok = r < HVV;
            int rc = ok ? r : 0;
            float rx = pvh[rc*3+0], ry = pvh[rc*3+1], rz = pvh[rc*3+2];
            float rr = fmaf(rx, rx, fmaf(ry, ry, rz * rz));
#pragma unroll
            for (int j = 0; j < 4; ++j) {
                float s = fmaf(m2x[j], rx, fmaf(m2y[j], ry, fmaf(m2z[j], rz, rr)));
                s = ok ? s : INFINITY;
                bool take = s < bd[j];
                bd[j] = take ? s : bd[j];
                bi[j] = take ? r : bi[j];
            }
        }
    }
#pragma unroll
    for (int j = 0; j < 4; ++j) {
        float d = bd[j]; int idx = bi[j];
#pragma unroll
        for (int off = 32; off; off >>= 1) {
            float od = __shfl_xor(d, off);
            int   oi = __shfl_xor(idx, off);
            if (od < d || (od == d && oi < idx)) { d = od; idx = oi; }
        }
        if (lane == 0) { sdp[g][h][j] = d; sip[g][h][j] = idx + h * HVV; }
    }

    __syncthreads();

    // ---- epilogue: lanes 0..7 of wave 0, one point each ----
    if (wave == 0) {
        float s = 0.f;
        if (lane < 8) {
            int gg = lane >> 2, q = lane & 3;

            float d0 = sdg[gg][0][q], d1 = sdg[gg][1][q];
            int   i0 = sig[gg][0][q], i1 = sig[gg][1][q];
            int gi = (d1 < d0 || (d1 == d0 && i1 < i0)) ? i1 : i0;

            float e0 = sdp[gg][0][q], e1 = sdp[gg][1][q];
            int   j0 = sip[gg][0][q], j1 = sip[gg][1][q];
            int pi = (e1 < e0 || (e1 == e0 && j1 < j0)) ? j1 : j0;

            int pidx = (blockIdx.x & 255) * 8 + lane;  // point in batch
            const float* pq = pp + ((size_t)b * PP + pidx) * 3;
            float px = pq[0], py = pq[1], pz = pq[2];

            const float* pvr = pv + ((size_t)b * VV + pi) * 3;
            float ex = px - pvr[0], ey = py - pvr[1], ez = pz - pvr[2];
            float el = fmaxf(sqrtf(fmaf(ex, ex, fmaf(ey, ey, ez * ez))), EPSF);

            const float* nb = nrm + ((size_t)b * NV + gi) * 3;
            float nx = nb[0], ny = nb[1], nz = nb[2];
            float nl = fmaxf(sqrtf(fmaf(nx, nx, fmaf(ny, ny, nz * nz))), EPSF);

            float dot = fmaf(ex, nx, fmaf(ey, ny, ez * nz));
            s = fabsf(dot) / (el * nl);
        }
        s += __shfl_xor(s, 1);
        s += __shfl_xor(s, 2);
        s += __shfl_xor(s, 4);
        if (lane == 0)
            atomicAdd(out, s * (1.f / (float)(BB * PP)));
    }
}

// ---------------------------------------------------------------------------
extern "C" void kernel_launch(void* const* d_in, const int* in_sizes, int n_in,
                              void* d_out, int out_size, void* d_ws, size_t ws_size,
                              hipStream_t stream) {
    const float* pp    = (const float*)d_in[0];  // pred_points   (8,2048,3)
    const float* pv    = (const float*)d_in[1];  // pred_vertices (8,2562,3)
    const float* gtv   = (const float*)d_in[2];  // gt_vertices   (8,8192,3)
    const int*   faces = (const int*)d_in[3];    // gt_faces      (8,16384,3)
    float* out = (float*)d_out;

    float* nrm = (float*)d_ws;  // (B, NV, 3) = 786432 B

    // Zero the scalar output (poisoned 0xAA before every launch).
    hipMemsetAsync(out, 0, sizeof(float), stream);

    face_normals_kernel<<<BB, 1024, 0, stream>>>(gtv, faces, nrm);

    nn_loss_kernel<<<(BB * PP) / 8, 256, 0, stream>>>(pp, pv, gtv, nrm, out);
}

// Round 7
// 162.891 us; speedup vs baseline: 1.8061x; 1.8061x over previous
//
#include <hip/hip_runtime.h>
#include <math.h>

#define BB 8
#define PP 2048
#define VV 2562
#define NV 8192
#define FF 16384
#define EPSF 1e-12f
#define NSLICE 4
#define FSLICE (FF / NSLICE)   // 4096 faces per block

// ---------------------------------------------------------------------------
// Kernel 1: per-face normals. 32 blocks = 8 batches x 4 face-slices, 1024
// threads each, private 98KB LDS accumulator per block (round-3 lesson: 8
// blocks = 8 CUs was gather-latency-bound at 190us; 32 blocks quadruples the
// L1/gather parallelism and cuts per-block work 4x). Merge step: contiguous
// global atomicAdd of the LDS copy into a single pre-zeroed nrm buffer --
// fully-covered 64B lines, no write amplification (round-0 lesson: the 36MB
// WRITE_SIZE was scattered atomics dirtying a full line per 4B add).
// ---------------------------------------------------------------------------
__global__ __launch_bounds__(1024) void face_normals_kernel(
    const float* __restrict__ gtv,   // (B, NV, 3)
    const int*   __restrict__ faces, // (B, FF, 3) int32
    float*       __restrict__ nrm)   // (B, NV, 3), pre-zeroed
{
    __shared__ float acc[NV * 3];    // 98304 B
    const int b = blockIdx.x >> 2;   // batch
    const int s = blockIdx.x & 3;    // face slice

    for (int i = threadIdx.x; i < NV * 3; i += 1024) acc[i] = 0.f;
    __syncthreads();

    const int*   fb = faces + ((size_t)b * FF + (size_t)s * FSLICE) * 3;
    const float* vb = gtv   + (size_t)b * NV * 3;

    for (int f = threadIdx.x; f < FSLICE; f += 1024) {
        int i0 = fb[f*3+0], i1 = fb[f*3+1], i2 = fb[f*3+2];

        float v0x = vb[i0*3+0], v0y = vb[i0*3+1], v0z = vb[i0*3+2];
        float v1x = vb[i1*3+0], v1y = vb[i1*3+1], v1z = vb[i1*3+2];
        float v2x = vb[i2*3+0], v2y = vb[i2*3+1], v2z = vb[i2*3+2];

        float e1x = v1x - v0x, e1y = v1y - v0y, e1z = v1z - v0z;
        float e2x = v2x - v0x, e2y = v2y - v0y, e2z = v2z - v0z;

        float fnx = e1y * e2z - e1z * e2y;
        float fny = e1z * e2x - e1x * e2z;
        float fnz = e1x * e2y - e1y * e2x;

        atomicAdd(&acc[i0*3+0], fnx); atomicAdd(&acc[i0*3+1], fny); atomicAdd(&acc[i0*3+2], fnz);
        atomicAdd(&acc[i1*3+0], fnx); atomicAdd(&acc[i1*3+1], fny); atomicAdd(&acc[i1*3+2], fnz);
        atomicAdd(&acc[i2*3+0], fnx); atomicAdd(&acc[i2*3+1], fny); atomicAdd(&acc[i2*3+2], fnz);
    }
    __syncthreads();

    // Contiguous, coalesced atomic merge (4 slices -> one buffer).
    float* nb = nrm + (size_t)b * NV * 3;
    for (int i = threadIdx.x; i < NV * 3; i += 1024) atomicAdd(&nb[i], acc[i]);
}

// ---------------------------------------------------------------------------
// Kernel 2: NN + loss (round-2 proven structure). One wave = 4 query points,
// lanes split the ref set (lane l scans refs l, l+64, ...). Inner score uses
// the reference's own expansion minus the argmin-invariant |q|^2 term:
//   s = rr - 2 q.r  ->  3 FMA + cmp + 2 cndmask per pair (6 VALU vs 9),
// rr amortized over the 4 points. Butterfly shfl argmin, lowest-index
// tie-break. Lane 0 computes the loss terms; one atomicAdd(out) per block.
// ---------------------------------------------------------------------------
__global__ __launch_bounds__(256) void nn_loss_kernel(
    const float* __restrict__ pp,   // (B, P, 3)  pred_points
    const float* __restrict__ pv,   // (B, V, 3)  pred_vertices
    const float* __restrict__ gtv,  // (B, NV, 3) gt_vertices
    const float* __restrict__ nrm,  // (B, NV, 3) gt vertex normals
    float*       __restrict__ out)  // scalar accumulator (pre-zeroed)
{
    const int lane = threadIdx.x & 63;
    const int wave = threadIdx.x >> 6;          // 0..3
    const int gw   = blockIdx.x * 4 + wave;     // global wave id 0..4095
    const int b    = gw >> 9;                   // 512 waves per batch
    const int p0   = (gw & 511) * 4;            // first of 4 points

    // Query points (wave-uniform loads, L1 broadcast); keep raw + doubled-neg.
    float px[4], py[4], pz[4], m2x[4], m2y[4], m2z[4];
    const float* ppb = pp + ((size_t)b * PP + p0) * 3;
#pragma unroll
    for (int j = 0; j < 4; ++j) {
        px[j] = ppb[j*3+0]; py[j] = ppb[j*3+1]; pz[j] = ppb[j*3+2];
        m2x[j] = -2.f * px[j]; m2y[j] = -2.f * py[j]; m2z[j] = -2.f * pz[j];
    }

    float bd[4]; int bi[4];

    // ---- scan gt_vertices: 8192 = 128 iters, no tail ----
#pragma unroll
    for (int j = 0; j < 4; ++j) { bd[j] = INFINITY; bi[j] = 0; }
    const float* gvb = gtv + (size_t)b * NV * 3;
    for (int i = 0; i < NV / 64; ++i) {
        int r = lane + i * 64;
        float rx = gvb[r*3+0], ry = gvb[r*3+1], rz = gvb[r*3+2];
        float rr = fmaf(rx, rx, fmaf(ry, ry, rz * rz));
#pragma unroll
        for (int j = 0; j < 4; ++j) {
            float s = fmaf(m2x[j], rx, fmaf(m2y[j], ry, fmaf(m2z[j], rz, rr)));
            bool take = s < bd[j];           // strict <: lowest idx per lane
            bd[j] = take ? s : bd[j];
            bi[j] = take ? r : bi[j];
        }
    }
    int gt_idx[4];
#pragma unroll
    for (int j = 0; j < 4; ++j) {
        float d = bd[j]; int idx = bi[j];
#pragma unroll
        for (int off = 32; off; off >>= 1) {
            float od = __shfl_xor(d, off);
            int   oi = __shfl_xor(idx, off);
            if (od < d || (od == d && oi < idx)) { d = od; idx = oi; }
        }
        gt_idx[j] = idx;
    }

    // ---- scan pred_vertices: 2562 = 41 iters, guarded tail ----
#pragma unroll
    for (int j = 0; j < 4; ++j) { bd[j] = INFINITY; bi[j] = 0; }
    const float* pvb = pv + (size_t)b * VV * 3;
    for (int i = 0; i < (VV + 63) / 64; ++i) {
        int r = lane + i * 64;
        bool ok = r < VV;
        int rc = ok ? r : 0;
        float rx = pvb[rc*3+0], ry = pvb[rc*3+1], rz = pvb[rc*3+2];
        float rr = fmaf(rx, rx, fmaf(ry, ry, rz * rz));
#pragma unroll
        for (int j = 0; j < 4; ++j) {
            float s = fmaf(m2x[j], rx, fmaf(m2y[j], ry, fmaf(m2z[j], rz, rr)));
            s = ok ? s : INFINITY;
            bool take = s < bd[j];
            bd[j] = take ? s : bd[j];
            bi[j] = take ? r : bi[j];
        }
    }
    int pr_idx[4];
#pragma unroll
    for (int j = 0; j < 4; ++j) {
        float d = bd[j]; int idx = bi[j];
#pragma unroll
        for (int off = 32; off; off >>= 1) {
            float od = __shfl_xor(d, off);
            int   oi = __shfl_xor(idx, off);
            if (od < d || (od == d && oi < idx)) { d = od; idx = oi; }
        }
        pr_idx[j] = idx;
    }

    // ---- loss terms (lane 0 of each wave) ----
    __shared__ float wsum[4];
    if (lane == 0) {
        const float* nb = nrm + (size_t)b * NV * 3;
        float s = 0.f;
#pragma unroll
        for (int j = 0; j < 4; ++j) {
            int vi = pr_idx[j];
            float ex = px[j] - pvb[vi*3+0];
            float ey = py[j] - pvb[vi*3+1];
            float ez = pz[j] - pvb[vi*3+2];
            float el = fmaxf(sqrtf(fmaf(ex, ex, fmaf(ey, ey, ez * ez))), EPSF);

            int ni = gt_idx[j];
            float nx = nb[ni*3+0];
            float ny = nb[ni*3+1];
            float nz = nb[ni*3+2];
            float nl = fmaxf(sqrtf(fmaf(nx, nx, fmaf(ny, ny, nz * nz))), EPSF);

            float dot = fmaf(ex, nx, fmaf(ey, ny, ez * nz));
            s += fabsf(dot) / (el * nl);
        }
        wsum[wave] = s;
    }
    __syncthreads();
    if (threadIdx.x == 0)
        atomicAdd(out, (wsum[0] + wsum[1] + wsum[2] + wsum[3]) *
                       (1.f / (float)(BB * PP)));
}

// ---------------------------------------------------------------------------
extern "C" void kernel_launch(void* const* d_in, const int* in_sizes, int n_in,
                              void* d_out, int out_size, void* d_ws, size_t ws_size,
                              hipStream_t stream) {
    const float* pp    = (const float*)d_in[0];  // pred_points   (8,2048,3)
    const float* pv    = (const float*)d_in[1];  // pred_vertices (8,2562,3)
    const float* gtv   = (const float*)d_in[2];  // gt_vertices   (8,8192,3)
    const int*   faces = (const int*)d_in[3];    // gt_faces      (8,16384,3)
    float* out = (float*)d_out;

    float* nrm = (float*)d_ws;  // (B, NV, 3) = 786432 B

    // Zero the normal accumulator and the scalar output (ws/out are
    // re-poisoned 0xAA before every timed launch).
    hipMemsetAsync(nrm, 0, (size_t)BB * NV * 3 * sizeof(float), stream);
    hipMemsetAsync(out, 0, sizeof(float), stream);

    face_normals_kernel<<<BB * NSLICE, 1024, 0, stream>>>(gtv, faces, nrm);

    nn_loss_kernel<<<(BB * PP) / 16, 256, 0, stream>>>(pp, pv, gtv, nrm, out);
}